// Round 1
// baseline (411.264 us; speedup 1.0000x reference)
//
#include <hip/hip_runtime.h>

#define IN_DIM 1024
#define N_NEURONS 1024
#define N_SOMA 16384
#define BT 32  // batch tile

typedef _Float16 half4 __attribute__((ext_vector_type(4)));

__device__ __forceinline__ float leaky(float v) { return v >= 0.0f ? v : 0.1f * v; }

// ---- K1: compact sparse dendrite weights ----
// pairs[s*32+p] = { bits(w), byte-offset of feature row in xs (= f*BT*2) }
__global__ void compact_kernel(const float* __restrict__ Wd,
                               const float* __restrict__ mask,
                               uint2* __restrict__ pairs) {
  const int lane = threadIdx.x & 63;
  const int s = (blockIdx.x << 2) + (threadIdx.x >> 6);  // one wave per soma row
  const float* mrow = mask + (size_t)s * IN_DIM;
  const float* wrow = Wd + (size_t)s * IN_DIM;
  int base = 0;
  for (int c = 0; c < IN_DIM / 64; ++c) {
    const int f = (c << 6) + lane;
    const float m = mrow[f];
    const unsigned long long b = __ballot(m != 0.0f);
    if (m != 0.0f) {
      const int pos = base + __popcll(b & ((1ull << lane) - 1ull));
      if (pos < 32)
        pairs[((size_t)s << 5) + pos] =
            make_uint2(__float_as_uint(wrow[f] * m), (unsigned)f << 6);
    }
    base += __popcll(b);
  }
}

// ---- K2: fused sparse-dendrite + block-diagonal soma layer ----
// grid: (B/BT, N_NEURONS/64), block: 512 (8 waves).
// Wave handles one neuron per iteration: lane = g*8 + j
//   g = soma sub-index (8 of 16 per pass, 2 passes), j = batch quad (4 of 32).
__global__ __launch_bounds__(512) void dendrite_kernel(
    const float* __restrict__ x, const uint2* __restrict__ pairs,
    const float* __restrict__ bd, const float* __restrict__ Ws,
    const float* __restrict__ bs, float* __restrict__ out) {
  __shared__ _Float16 xs[IN_DIM * BT];  // [feature][batch] f16, 64 KB
  const int b0 = blockIdx.x * BT;

  // stage x tile: b-minor thread mapping -> conflict-free LDS writes
  for (int q = threadIdx.x; q < (IN_DIM / 4) * BT; q += 512) {
    const int b = q & (BT - 1);
    const int fq = q >> 5;  // float4 index within row
    const float4 v = ((const float4*)(x + (size_t)(b0 + b) * IN_DIM))[fq];
    const int f = fq << 2;
    xs[(f + 0) * BT + b] = (_Float16)v.x;
    xs[(f + 1) * BT + b] = (_Float16)v.y;
    xs[(f + 2) * BT + b] = (_Float16)v.z;
    xs[(f + 3) * BT + b] = (_Float16)v.w;
  }
  __syncthreads();

  const int lane = threadIdx.x & 63;
  const int wv = threadIdx.x >> 6;  // wave id 0..7
  const int g = lane >> 3;          // soma sub-index
  const int j = lane & 7;           // batch quad
  const char* xbase = (const char*)xs + (j << 3);

  for (int it = 0; it < 8; ++it) {
    const int i = (blockIdx.y << 6) + (it << 3) + wv;  // neuron
    float p0 = 0.f, p1 = 0.f, p2 = 0.f, p3 = 0.f;
#pragma unroll
    for (int pass = 0; pass < 2; ++pass) {
      const int s = (i << 4) + (pass << 3) + g;
      const uint4* pr = (const uint4*)(pairs + ((size_t)s << 5));
      float a0 = 0.f, a1 = 0.f, a2 = 0.f, a3 = 0.f;
#pragma unroll
      for (int k2 = 0; k2 < 16; ++k2) {
        const uint4 p = pr[k2];
        {
          const float w = __uint_as_float(p.x);
          const half4 xv = *(const half4*)(xbase + p.y);
          a0 += (float)xv.x * w;
          a1 += (float)xv.y * w;
          a2 += (float)xv.z * w;
          a3 += (float)xv.w * w;
        }
        {
          const float w = __uint_as_float(p.z);
          const half4 xv = *(const half4*)(xbase + p.w);
          a0 += (float)xv.x * w;
          a1 += (float)xv.y * w;
          a2 += (float)xv.z * w;
          a3 += (float)xv.w * w;
        }
      }
      const float bdv = bd[s];
      const float wsv = Ws[(size_t)i * N_SOMA + s];  // block-diagonal element
      p0 += leaky(a0 + bdv) * wsv;
      p1 += leaky(a1 + bdv) * wsv;
      p2 += leaky(a2 + bdv) * wsv;
      p3 += leaky(a3 + bdv) * wsv;
    }
    // reduce the 8 soma-groups (lane bits 3..5)
#pragma unroll
    for (int d = 8; d <= 32; d <<= 1) {
      p0 += __shfl_xor(p0, d);
      p1 += __shfl_xor(p1, d);
      p2 += __shfl_xor(p2, d);
      p3 += __shfl_xor(p3, d);
    }
    if (lane < 8) {
      const float bsv = bs[i];
      float* o = out + (size_t)(b0 + (lane << 2)) * N_NEURONS + i;
      o[0 * N_NEURONS] = leaky(p0 + bsv);
      o[1 * N_NEURONS] = leaky(p1 + bsv);
      o[2 * N_NEURONS] = leaky(p2 + bsv);
      o[3 * N_NEURONS] = leaky(p3 + bsv);
    }
  }
}

extern "C" void kernel_launch(void* const* d_in, const int* in_sizes, int n_in,
                              void* d_out, int out_size, void* d_ws, size_t ws_size,
                              hipStream_t stream) {
  const float* x = (const float*)d_in[0];
  const float* Wd = (const float*)d_in[1];
  const float* bd = (const float*)d_in[2];
  const float* Ws = (const float*)d_in[3];
  const float* bs = (const float*)d_in[4];
  const float* dmask = (const float*)d_in[5];
  float* out = (float*)d_out;

  uint2* pairs = (uint2*)d_ws;  // N_SOMA*32*8B = 4 MB scratch

  const int B = in_sizes[0] / IN_DIM;  // 4096

  compact_kernel<<<dim3(N_SOMA / 4), dim3(256), 0, stream>>>(Wd, dmask, pairs);
  dendrite_kernel<<<dim3(B / BT, N_NEURONS / 64), dim3(512), 0, stream>>>(
      x, pairs, bd, Ws, bs, out);
}

// Round 2
// 385.457 us; speedup vs baseline: 1.0670x; 1.0670x over previous
//
#include <hip/hip_runtime.h>

#define IN_DIM 1024
#define N_NEURONS 1024
#define N_SOMA 16384
#define BT 64          // batch tile (row = 64 f16 = 128 B = full bank period)
#define NB 4096        // batch size

typedef _Float16 h8 __attribute__((ext_vector_type(8)));

__device__ __forceinline__ float leaky(float v) { return v >= 0.0f ? v : 0.1f * v; }

// ---- K0: transpose x [B][F] f32 -> xt tiled [bt][f][64] f16 ----
// grid (4, 64): blockIdx.x = f-chunk(256), blockIdx.y = batch tile. 256 thr.
__global__ void transpose_kernel(const float* __restrict__ x,
                                 _Float16* __restrict__ xt) {
  const int f = blockIdx.x * 256 + threadIdx.x;
  const int bt = blockIdx.y;
  const int b0 = bt * BT;
  h8* dst = (h8*)xt + ((size_t)bt * IN_DIM + f) * 8;
#pragma unroll
  for (int o = 0; o < 8; ++o) {
    h8 v;
#pragma unroll
    for (int e = 0; e < 8; ++e)
      v[e] = (_Float16)x[(size_t)(b0 + o * 8 + e) * IN_DIM + f];
    dst[o] = v;
  }
}

// ---- K1: compact sparse dendrite weights ----
// One wave per soma row; lane covers 16 features. No serial ballot chain.
// pairs[s*32+p] = { f32 bits of w, byte offset f*128 in xs }
__global__ void compact_kernel(const float* __restrict__ Wd,
                               const float* __restrict__ mask,
                               uint2* __restrict__ pairs) {
  const int lane = threadIdx.x & 63;
  const int s = (blockIdx.x << 2) + (threadIdx.x >> 6);
  const float* mrow = mask + (size_t)s * IN_DIM + lane * 16;
  const float* wrow = Wd + (size_t)s * IN_DIM + lane * 16;
  float m[16], w[16];
#pragma unroll
  for (int k = 0; k < 4; ++k) {
    *(float4*)(m + 4 * k) = *(const float4*)(mrow + 4 * k);
    *(float4*)(w + 4 * k) = *(const float4*)(wrow + 4 * k);
  }
  int c = 0;
#pragma unroll
  for (int k = 0; k < 16; ++k) c += (m[k] != 0.0f) ? 1 : 0;
  // inclusive prefix over lanes -> exclusive
  int inc = c;
#pragma unroll
  for (int d = 1; d < 64; d <<= 1) {
    int t = __shfl_up(inc, d);
    if (lane >= d) inc += t;
  }
  int pos = inc - c;
  uint2* prow = pairs + ((size_t)s << 5);
#pragma unroll
  for (int k = 0; k < 16; ++k) {
    if (m[k] != 0.0f) {
      if (pos < 32)
        prow[pos] = make_uint2(__float_as_uint(w[k] * m[k]),
                               (unsigned)(lane * 16 + k) << 7);
      ++pos;
    }
  }
}

// ---- K2: fused sparse-dendrite + block-diagonal soma layer ----
// grid (8, 64): x = neuron tile (128 neurons), y = batch tile (64 b).
// block 1024 = 16 waves; wave = 8 neurons (n=lane>>3) x 8 batch-octs (j=lane&7).
// Each lane owns a full neuron for 8 batches: 16 dendrites serial, no shuffles.
__global__ __launch_bounds__(1024) void dendrite_kernel(
    const _Float16* __restrict__ xt, const uint2* __restrict__ pairs,
    const float* __restrict__ bd, const float* __restrict__ Ws,
    const float* __restrict__ bs, float* __restrict__ out) {
  __shared__ _Float16 xs[IN_DIM * BT];  // 128 KB, row f = 128 B
  // stage: straight coalesced copy (xt already f16 in tile layout)
  const uint4* src = (const uint4*)(xt + (size_t)blockIdx.y * IN_DIM * BT);
  uint4* dst = (uint4*)xs;
  for (int q = threadIdx.x; q < IN_DIM * BT * 2 / 16; q += 1024) dst[q] = src[q];
  __syncthreads();

  const int lane = threadIdx.x & 63;
  const int wv = threadIdx.x >> 6;  // 0..15
  const int n = lane >> 3;          // neuron within wave
  const int j = lane & 7;           // batch oct
  const int i = blockIdx.x * 128 + wv * 8 + n;  // neuron id
  const char* xb = (const char*)xs + (j << 4);

  float p[8] = {0.f, 0.f, 0.f, 0.f, 0.f, 0.f, 0.f, 0.f};
  const float* wsrow = Ws + (size_t)i * N_SOMA + (i << 4);
  const float* bdrow = bd + (i << 4);

  for (int g = 0; g < 16; ++g) {
    const uint4* pr = (const uint4*)(pairs + (((size_t)(i << 4) + g) << 5));
    float a[8] = {0.f, 0.f, 0.f, 0.f, 0.f, 0.f, 0.f, 0.f};
#pragma unroll
    for (int k = 0; k < 16; ++k) {
      const uint4 p4 = pr[k];
      {
        const float w = __uint_as_float(p4.x);
        const h8 xv = *(const h8*)(xb + p4.y);
#pragma unroll
        for (int q = 0; q < 8; ++q) a[q] = fmaf((float)xv[q], w, a[q]);
      }
      {
        const float w = __uint_as_float(p4.z);
        const h8 xv = *(const h8*)(xb + p4.w);
#pragma unroll
        for (int q = 0; q < 8; ++q) a[q] = fmaf((float)xv[q], w, a[q]);
      }
    }
    const float bdv = bdrow[g];
    const float wsv = wsrow[g];
#pragma unroll
    for (int q = 0; q < 8; ++q) p[q] = fmaf(leaky(a[q] + bdv), wsv, p[q]);
  }
  const float bsv = bs[i];
  const int b0 = blockIdx.y * BT + j * 8;
#pragma unroll
  for (int q = 0; q < 8; ++q)
    out[(size_t)(b0 + q) * N_NEURONS + i] = leaky(p[q] + bsv);
}

extern "C" void kernel_launch(void* const* d_in, const int* in_sizes, int n_in,
                              void* d_out, int out_size, void* d_ws, size_t ws_size,
                              hipStream_t stream) {
  const float* x = (const float*)d_in[0];
  const float* Wd = (const float*)d_in[1];
  const float* bd = (const float*)d_in[2];
  const float* Ws = (const float*)d_in[3];
  const float* bs = (const float*)d_in[4];
  const float* dmask = (const float*)d_in[5];
  float* out = (float*)d_out;

  uint2* pairs = (uint2*)d_ws;                          // 4 MB
  _Float16* xt = (_Float16*)((char*)d_ws + (4 << 20));  // 8 MB

  transpose_kernel<<<dim3(4, NB / BT), dim3(256), 0, stream>>>(x, xt);
  compact_kernel<<<dim3(N_SOMA / 4), dim3(256), 0, stream>>>(Wd, dmask, pairs);
  dendrite_kernel<<<dim3(N_NEURONS / 128, NB / BT), dim3(1024), 0, stream>>>(
      xt, pairs, bd, Ws, bs, out);
}